// Round 4
// baseline (38947.491 us; speedup 1.0000x reference)
//
#include <hip/hip_runtime.h>
#include <stdint.h>

typedef __attribute__((ext_vector_type(4))) float f32x4;

#define T_STEPS 4096
#define HID 1024
#define NBLK 256

// ---------------------------------------------------------------------------
// Fully fused persistent LSTM, fp32 I/O (the reference's actual dtypes).
// 256 blocks x 256 threads, 1 block/CU.
// Block b owns hidden units [4b, 4b+4) -> 16 gate columns
//   col(c) = (c>>2)*1024 + b*4 + (c&3),  c = tid & 15.
// Thread (c = tid&15, s = tid>>4) holds BOTH U[64s..64s+64)[col] and
// W[64s..64s+64)[col] in fp32 registers (128 VGPRs) and each step computes
//   acc = sum_i ( h[64s+i]*Ureg[i] + x_t[64s+i]*Wreg[i] )   (128 FMAs)
// xW is never materialized; workspace use is 24 KB.
// Grid barrier: one counter per step, agent-scope release/acquire.
// h_gbl double-buffered by parity (t+1)&1: reads of buffer p at step t
// precede the release-arrival at cnt[t+1] in program order; the next write
// to parity p (at step t+2) happens only after the writer acquires
// cnt[t+1] == NBLK. Race-free with blocks at most one barrier apart.
// ---------------------------------------------------------------------------
__global__ __launch_bounds__(256) void lstm_fused(
    const float* __restrict__ x,    // [4096,1024] f32
    const float* __restrict__ W,    // [1024,4096] f32
    const float* __restrict__ U,    // [1024,4096] f32
    const float* __restrict__ bias, // [4096] f32
    float* __restrict__ out,        // hidden_seq [4096,1024] + h_T + c_T (f32)
    float* __restrict__ h_gbl,      // [2][1024] f32
    unsigned int* __restrict__ cnt) // [4096] u32, zeroed
{
    const int tid  = threadIdx.x;
    const int b    = blockIdx.x;
    const int c    = tid & 15;
    const int s    = tid >> 4;
    const int col  = (c >> 2) * 1024 + b * 4 + (c & 3);
    const int lane = tid & 63;
    const int wave = tid >> 6;

    __shared__ float h_lds[16 * 68];     // h[k] at (k>>6)*68 + (k&63)
    __shared__ float x_lds[2][16 * 68];  // same padded layout
    __shared__ float red[64];
    __shared__ float bias_l[16];

    // --- one-time: U and W columns into registers ---
    float Ureg[64], Wreg[64];
    #pragma unroll
    for (int i = 0; i < 64; ++i) {
        const size_t r = (size_t)(s * 64 + i) * 4096 + col;
        Ureg[i] = U[r];
        Wreg[i] = W[r];
    }
    if (tid < 16) bias_l[tid] = bias[col];

    for (int i = tid; i < 16 * 68; i += 256) h_lds[i] = 0.0f;  // h0 = 0

    // stage x row 0; prefetch x row 1 (thread covers k = 4*tid .. 4*tid+3)
    const int xofs = (tid >> 4) * 68 + (tid & 15) * 4;
    *(f32x4*)&x_lds[0][xofs] = *(const f32x4*)(x + (size_t)tid * 4);
    f32x4 xpre = *(const f32x4*)(x + (size_t)1024 + tid * 4);
    __syncthreads();

    const int hbase = s * 68;
    float c_reg = 0.0f;   // cell state, live in threads tid<4

    for (int t = 0; t < T_STEPS; ++t) {
        const int cur = t & 1, nxt = cur ^ 1;

        // 1: fused dot  acc = U.h_{t-1} + W.x_t  over this thread's 64-chunk
        float acc = 0.0f;
        #pragma unroll
        for (int i = 0; i < 16; ++i) {
            f32x4 h4 = *(const f32x4*)&h_lds[hbase + 4 * i];
            f32x4 x4 = *(const f32x4*)&x_lds[cur][hbase + 4 * i];
            acc += h4.x * Ureg[4*i]   + h4.y * Ureg[4*i+1]
                 + h4.z * Ureg[4*i+2] + h4.w * Ureg[4*i+3]
                 + x4.x * Wreg[4*i]   + x4.y * Wreg[4*i+1]
                 + x4.z * Wreg[4*i+2] + x4.w * Wreg[4*i+3];
        }
        // 2: reduce lanes {c, c+16, c+32, c+48} -> red[wave*16 + c]
        acc += __shfl_down(acc, 32);
        acc += __shfl_down(acc, 16);
        if (lane < 16) red[wave * 16 + lane] = acc;

        // rotate x double-buffer: write x_{t+1}, prefetch x_{t+2}
        *(f32x4*)&x_lds[nxt][xofs] = xpre;
        {
            const int tp = (t + 2 < T_STEPS) ? (t + 2) : (T_STEPS - 1);
            xpre = *(const f32x4*)(x + (size_t)tp * 1024 + tid * 4);
        }
        __syncthreads();   // [B1] red + x_lds[nxt] visible

        // 3: gates + activations in threads tid<4 (hidden unit b*4+tid)
        if (tid < 4) {
            const float gi = red[tid]      + red[16 + tid] + red[32 + tid] + red[48 + tid] + bias_l[tid];
            const float gf = red[4 + tid]  + red[20 + tid] + red[36 + tid] + red[52 + tid] + bias_l[4 + tid];
            const float gg = red[8 + tid]  + red[24 + tid] + red[40 + tid] + red[56 + tid] + bias_l[8 + tid];
            const float go = red[12 + tid] + red[28 + tid] + red[44 + tid] + red[60 + tid] + bias_l[12 + tid];
            const float iv = 1.0f / (1.0f + __expf(-gi));
            const float fv = 1.0f / (1.0f + __expf(-gf));
            const float gv = tanhf(gg);
            const float ov = 1.0f / (1.0f + __expf(-go));
            const float cn = fv * c_reg + iv * gv;
            c_reg = cn;
            const float hn = ov * tanhf(cn);
            const int jj = b * 4 + tid;
            out[(size_t)t * HID + jj] = hn;
            if (t == T_STEPS - 1) {
                out[(size_t)T_STEPS * HID + jj] = hn;         // h_T
                out[(size_t)T_STEPS * HID + HID + jj] = cn;   // c_T
            } else {
                __hip_atomic_store(&h_gbl[((t + 1) & 1) * 1024 + jj], hn,
                                   __ATOMIC_RELAXED, __HIP_MEMORY_SCOPE_AGENT);
            }
        }
        if (t == T_STEPS - 1) break;
        __syncthreads();   // [B2] h stores drained block-wide

        // 4: grid barrier (counter per step)
        if (tid == 0) {
            __hip_atomic_fetch_add(&cnt[t], 1u, __ATOMIC_RELEASE, __HIP_MEMORY_SCOPE_AGENT);
            while (__hip_atomic_load(&cnt[t], __ATOMIC_ACQUIRE, __HIP_MEMORY_SCOPE_AGENT) < NBLK)
                __builtin_amdgcn_s_sleep(1);
        }
        __syncthreads();   // [B3]

        // 5: stage h_t (just produced) from h_gbl into LDS
        const float* hb = h_gbl + ((t + 1) & 1) * 1024;
        #pragma unroll
        for (int q = 0; q < 4; ++q) {
            const int k = tid + 256 * q;
            const float v = __hip_atomic_load(&hb[k], __ATOMIC_RELAXED, __HIP_MEMORY_SCOPE_AGENT);
            h_lds[(k >> 6) * 68 + (k & 63)] = v;
        }
        __syncthreads();   // [B4]
    }
}

extern "C" void kernel_launch(void* const* d_in, const int* in_sizes, int n_in,
                              void* d_out, int out_size, void* d_ws, size_t ws_size,
                              hipStream_t stream) {
    const float* x    = (const float*)d_in[0];  // [4096,1024]
    const float* W    = (const float*)d_in[1];  // [1024,4096]
    const float* U    = (const float*)d_in[2];  // [1024,4096]
    const float* bias = (const float*)d_in[3];  // [4096]
    float* out = (float*)d_out;                 // [4096*1024 + 1024 + 1024]

    // Workspace: h_gbl [2][1024] f32 (8 KB) @ +0, cnt [4096] u32 (16 KB) @ +8192.
    char* ws = (char*)d_ws;
    float* h_gbl      = (float*)ws;
    unsigned int* cnt = (unsigned int*)(ws + 8192);

    hipMemsetAsync(cnt, 0, T_STEPS * sizeof(unsigned int), stream);
    lstm_fused<<<NBLK, 256, 0, stream>>>(x, W, U, bias, out, h_gbl, cnt);
}

// Round 5
// 34139.941 us; speedup vs baseline: 1.1408x; 1.1408x over previous
//
#include <hip/hip_runtime.h>
#include <stdint.h>

typedef __attribute__((ext_vector_type(4))) float f32x4;

#define T_STEPS 4096
#define HID 1024
#define NBLK 256

// ---------------------------------------------------------------------------
// Fully fused persistent LSTM, fp32. 256 blocks x 256 threads, 1 block/CU.
// Block b owns hidden units [4b,4b+4) -> 16 gate columns
//   col(c) = (c>>2)*1024 + b*4 + (c&3), c = tid&15.
// Thread (c, s=tid>>4) holds U[64s..64s+64)[col] and W[...][col] in VGPRs
// (128 f32; __launch_bounds__(256,1) so the allocator does NOT spill them —
// round-4 VGPR_Count=92 proved the arrays were spilled, costing ~9x).
//
// Per step critical path:  U.h dot (W.x part precomputed during the previous
// barrier wait) -> shuffle+LDS reduce -> tid0: gates for all 4 units ->
// plain f32x4 h-store published by a RELEASE arrival-add -> hierarchical
// barrier (8 lines x 32 RMWs, then 8 RMWs on a final flag; relaxed poll +
// one ACQUIRE load) -> all threads stage h via plain f32x4 loads.
//
// Barrier slots are parity-4 recycled; slot (t-1)&3 is reset by blocks 0..7
// after PASSING barrier t (at that point fin[t]==8 => every block exited the
// poll of t-1, and the reset happens-before any slot reuse at t+3 via the
// resetter's release-arrival at t+1 -> barrier HB chain).
// Workspace: bar 4.5 KB @ +0, h_gbl [2][1024] f32 @ +8192. Total 16 KB.
// ---------------------------------------------------------------------------
__global__ __launch_bounds__(256, 1) void lstm_fused(
    const float* __restrict__ x,    // [4096,1024]
    const float* __restrict__ W,    // [1024,4096]
    const float* __restrict__ U,    // [1024,4096]
    const float* __restrict__ bias, // [4096]
    float* __restrict__ out,        // [4096*1024 + 1024 + 1024]
    float* __restrict__ h_gbl,      // [2][1024] f32
    unsigned int* __restrict__ bar) // arr[4][8]*32u + fin[4]*32u, zeroed
{
    const int tid  = threadIdx.x;
    const int b    = blockIdx.x;
    const int c    = tid & 15;
    const int s    = tid >> 4;
    const int col  = (c >> 2) * 1024 + b * 4 + (c & 3);
    const int lane = tid & 63;
    const int wave = tid >> 6;
    const int grp  = b & 7;          // ~XCD id (round-robin dispatch)

    __shared__ __align__(16) float h_lds[16 * 68];     // h[k] at (k>>6)*68+(k&63)
    __shared__ __align__(16) float x_lds[2][16 * 68];
    __shared__ __align__(16) float red[64];
    __shared__ __align__(16) float bias_l[16];

    float Ureg[64], Wreg[64];
    #pragma unroll
    for (int i = 0; i < 64; ++i) {
        const size_t r = (size_t)(s * 64 + i) * 4096 + col;
        Ureg[i] = U[r];
        Wreg[i] = W[r];
    }
    if (tid < 16) bias_l[tid] = bias[col];

    for (int i = tid; i < 16 * 68; i += 256) h_lds[i] = 0.0f;   // h0 = 0
    const int xofs = (tid >> 4) * 68 + (tid & 15) * 4;
    *(f32x4*)&x_lds[0][xofs] = *(const f32x4*)(x + (size_t)tid * 4);
    f32x4 xpre = *(const f32x4*)(x + 1024 + (size_t)tid * 4);
    __syncthreads();

    const int hbase = s * 68;

    // prologue: W.x_0 partial (4 independent FMA chains for ILP)
    float acc_x;
    {
        float a0 = 0.f, a1 = 0.f, a2 = 0.f, a3 = 0.f;
        #pragma unroll
        for (int i = 0; i < 16; ++i) {
            f32x4 x4 = *(const f32x4*)&x_lds[0][hbase + 4 * i];
            a0 += x4.x * Wreg[4*i];   a1 += x4.y * Wreg[4*i+1];
            a2 += x4.z * Wreg[4*i+2]; a3 += x4.w * Wreg[4*i+3];
        }
        acc_x = (a0 + a1) + (a2 + a3);
    }

    f32x4 cvec = {0.f, 0.f, 0.f, 0.f};   // cell state (tid0 only uses it)
    unsigned int* arr_base = bar;              // arr[slot][g] at (slot*8+g)*32
    unsigned int* fin_base = bar + 4 * 8 * 32; // fin[slot]   at slot*32

    for (int t = 0; t < T_STEPS; ++t) {
        const int nxt = (t + 1) & 1;

        // 1: acc = W.x_t (precomputed) + U.h_{t-1}
        float acc;
        {
            float a0 = 0.f, a1 = 0.f, a2 = 0.f, a3 = 0.f;
            #pragma unroll
            for (int i = 0; i < 16; ++i) {
                f32x4 h4 = *(const f32x4*)&h_lds[hbase + 4 * i];
                a0 += h4.x * Ureg[4*i];   a1 += h4.y * Ureg[4*i+1];
                a2 += h4.z * Ureg[4*i+2]; a3 += h4.w * Ureg[4*i+3];
            }
            acc = acc_x + ((a0 + a1) + (a2 + a3));
        }
        // 2: lanes {c, c+16, c+32, c+48} share a column
        acc += __shfl_down(acc, 32);
        acc += __shfl_down(acc, 16);
        if (lane < 16) red[wave * 16 + lane] = acc;

        // rotate x double-buffer: write x_{t+1}, prefetch x_{t+2}
        *(f32x4*)&x_lds[nxt][xofs] = xpre;
        {
            const int tp = (t + 2 < T_STEPS) ? (t + 2) : (T_STEPS - 1);
            xpre = *(const f32x4*)(x + (size_t)tp * 1024 + tid * 4);
        }
        __syncthreads();   // [S1] red + x_lds[nxt] visible

        // 3: ALL threads compute W.x_{t+1} now — overlaps tid0's serial
        //    section and the barrier wait below.
        {
            float a0 = 0.f, a1 = 0.f, a2 = 0.f, a3 = 0.f;
            #pragma unroll
            for (int i = 0; i < 16; ++i) {
                f32x4 x4 = *(const f32x4*)&x_lds[nxt][hbase + 4 * i];
                a0 += x4.x * Wreg[4*i];   a1 += x4.y * Wreg[4*i+1];
                a2 += x4.z * Wreg[4*i+2]; a3 += x4.w * Wreg[4*i+3];
            }
            acc_x = (a0 + a1) + (a2 + a3);
        }

        // 4: tid0 alone: gates for all 4 hidden units, publish h, barrier
        if (tid == 0) {
            f32x4 g0 = {0,0,0,0}, g1 = {0,0,0,0}, g2 = {0,0,0,0}, g3 = {0,0,0,0};
            #pragma unroll
            for (int w = 0; w < 4; ++w) {
                g0 += *(const f32x4*)&red[w * 16 + 0];
                g1 += *(const f32x4*)&red[w * 16 + 4];
                g2 += *(const f32x4*)&red[w * 16 + 8];
                g3 += *(const f32x4*)&red[w * 16 + 12];
            }
            g0 += *(const f32x4*)&bias_l[0];
            g1 += *(const f32x4*)&bias_l[4];
            g2 += *(const f32x4*)&bias_l[8];
            g3 += *(const f32x4*)&bias_l[12];
            f32x4 hvec;
            #pragma unroll
            for (int u = 0; u < 4; ++u) {
                const float iv = 1.0f / (1.0f + __expf(-g0[u]));
                const float fv = 1.0f / (1.0f + __expf(-g1[u]));
                const float gv = tanhf(g2[u]);
                const float ov = 1.0f / (1.0f + __expf(-g3[u]));
                const float cn = fv * cvec[u] + iv * gv;
                cvec[u] = cn;
                hvec[u] = ov * tanhf(cn);
            }
            if (t == T_STEPS - 1) {
                *(f32x4*)(out + (size_t)t * HID + b * 4) = hvec;
                *(f32x4*)(out + (size_t)T_STEPS * HID + b * 4) = hvec;          // h_T
                *(f32x4*)(out + (size_t)T_STEPS * HID + HID + b * 4) = cvec;    // c_T
            } else {
                // publish h (plain store; the RELEASE arrival-add orders it)
                *(f32x4*)(h_gbl + nxt * 1024 + b * 4) = hvec;
                unsigned int* arr = arr_base + ((size_t)(t & 3) * 8 + grp) * 32;
                unsigned int* fin = fin_base + (size_t)(t & 3) * 32;
                const unsigned int old =
                    __hip_atomic_fetch_add(arr, 1u, __ATOMIC_RELEASE, __HIP_MEMORY_SCOPE_AGENT);
                if (old == 31u)
                    __hip_atomic_fetch_add(fin, 1u, __ATOMIC_ACQ_REL, __HIP_MEMORY_SCOPE_AGENT);
                *(f32x4*)(out + (size_t)t * HID + b * 4) = hvec;  // off the drain path
                while (__hip_atomic_load(fin, __ATOMIC_RELAXED, __HIP_MEMORY_SCOPE_AGENT) < 8u)
                    __builtin_amdgcn_s_sleep(1);
                (void)__hip_atomic_load(fin, __ATOMIC_ACQUIRE, __HIP_MEMORY_SCOPE_AGENT);
                // recycle slot (t-1)&3 (proof of safety in header comment)
                if (b < 8) {
                    const int prev = (t - 1) & 3;
                    __hip_atomic_store(arr_base + ((size_t)prev * 8 + b) * 32, 0u,
                                       __ATOMIC_RELAXED, __HIP_MEMORY_SCOPE_AGENT);
                    if (b == 0)
                        __hip_atomic_store(fin_base + (size_t)prev * 32, 0u,
                                           __ATOMIC_RELAXED, __HIP_MEMORY_SCOPE_AGENT);
                }
            }
        }
        if (t == T_STEPS - 1) break;
        __syncthreads();   // [S2] barrier passed block-wide

        // 5: stage h_t (one f32x4 per thread; HB via acquire + syncthreads)
        f32x4 hv = *(const f32x4*)(h_gbl + nxt * 1024 + tid * 4);
        *(f32x4*)&h_lds[xofs] = hv;
        __syncthreads();   // [S3]
    }
}

extern "C" void kernel_launch(void* const* d_in, const int* in_sizes, int n_in,
                              void* d_out, int out_size, void* d_ws, size_t ws_size,
                              hipStream_t stream) {
    const float* x    = (const float*)d_in[0];
    const float* W    = (const float*)d_in[1];
    const float* U    = (const float*)d_in[2];
    const float* bias = (const float*)d_in[3];
    float* out = (float*)d_out;

    // Workspace: bar (arr[4][8] + fin[4], 128B-strided) @ +0 (4.5 KB, zeroed),
    //            h_gbl [2][1024] f32 @ +8192 (written before read). 16 KB total.
    char* ws = (char*)d_ws;
    unsigned int* bar = (unsigned int*)ws;
    float* h_gbl      = (float*)(ws + 8192);

    hipMemsetAsync(bar, 0, 8192, stream);
    lstm_fused<<<NBLK, 256, 0, stream>>>(x, W, U, bias, out, h_gbl, bar);
}